// Round 5
// baseline (3598.817 us; speedup 1.0000x reference)
//
#include <hip/hip_runtime.h>
#include <hip/hip_bf16.h>
#include <cstdint>

typedef short short8 __attribute__((ext_vector_type(8)));
typedef float f32x4 __attribute__((ext_vector_type(4)));
typedef uint32_t u32x2 __attribute__((ext_vector_type(2)));
typedef unsigned short u16;

#define DEVINL __device__ __forceinline__

DEVINL u16 f32_to_bf16(float f) {
  uint32_t u = __builtin_bit_cast(uint32_t, f);
  u += 0x7FFFu + ((u >> 16) & 1u);   // RTNE; inputs are finite
  return (u16)(u >> 16);
}
DEVINL float bf16_to_f32(u16 b) {
  return __builtin_bit_cast(float, ((uint32_t)b) << 16);
}
DEVINL f32x4 mfma16(short8 a, short8 b, f32x4 c) {
  return __builtin_amdgcn_mfma_f32_16x16x32_bf16(a, b, c, 0, 0, 0);
}
// tanh(x) = 1 - 2/(1+e^{2x}); e^{2x} = exp2(x * 2*log2(e)). Inf-safe at both ends.
DEVINL float tanh_e2(float x) {
  float e = __builtin_amdgcn_exp2f(x * 2.88539008177793f);
  return 1.f - __fdividef(2.f, 1.f + e);
}

// ---------------- fp32 -> bf16 convert ----------------
__global__ void conv_bf16(const float* __restrict__ src, u16* __restrict__ dst, long n) {
  long i = ((long)blockIdx.x * blockDim.x + threadIdx.x) * 4;
  long stride = (long)gridDim.x * blockDim.x * 4;
  for (; i < n; i += stride) {
    float4 v = *(const float4*)(src + i);
    uint64_t p = (uint64_t)f32_to_bf16(v.x)
               | ((uint64_t)f32_to_bf16(v.y) << 16)
               | ((uint64_t)f32_to_bf16(v.z) << 32)
               | ((uint64_t)f32_to_bf16(v.w) << 48);
    *(uint64_t*)(dst + i) = p;
  }
}

__global__ void prep_bias(const float* __restrict__ bih, const float* __restrict__ bhh,
                          float* __restrict__ b1, float* __restrict__ b2) {
  int i = threadIdx.x;   // 512 threads
  b1[i] = bih[i]       + bhh[i];
  b2[i] = bih[512 + i] + bhh[512 + i];
}

// ---------------- GEMM: C[M,N] = A[M,K] @ B[N,K]^T + bias ----------------
// MODE 0: float out, [M][N] (FC head).
// MODE 1: bf16 out scattered into rec2's U fragment layout:
//   (b,t,j): hB=j>>8, w=(j>>5)&7, tt=(j>>4)&1, q=(j>>2)&3, rg=j&3
//   bx = hB*8 + (b>>4); tid = w*64 + q*16 + (b&15)
//   u16 idx = ((t*16 + bx)*512 + tid)*8 + tt*4 + rg
template <int MODE>
__launch_bounds__(512, 2)
__global__ void gemm_bt(const u16* __restrict__ A, const u16* __restrict__ B,
                        const float* __restrict__ bias, void* __restrict__ out,
                        int M, int N, int K) {
  __shared__ u16 lA[128 * 64];
  __shared__ u16 lB[128 * 64];
  const int tid  = threadIdx.x;
  const int lane = tid & 63;
  const int wave = tid >> 6;
  const int wr = wave >> 2;
  const int wc = wave & 3;
  const int q   = lane >> 4;
  const int r16 = lane & 15;
  const int brow = blockIdx.x * 128;
  const int bcol = blockIdx.y * 128;

  f32x4 acc[4][2];
#pragma unroll
  for (int i = 0; i < 4; ++i)
#pragma unroll
    for (int j = 0; j < 2; ++j) acc[i][j] = (f32x4){0.f, 0.f, 0.f, 0.f};

  const int nkt = K >> 6;
  for (int kt = 0; kt < nkt; ++kt) {
#pragma unroll
    for (int s = 0; s < 2; ++s) {
      int c   = tid * 2 + s;
      int row = c >> 3;
      int cb  = (c & 7) * 16;
      int dsw = cb ^ ((row & 7) << 4);
      short8 va = *(const short8*)(A + (size_t)(brow + row) * K + kt * 64 + (cb >> 1));
      *(short8*)((char*)lA + row * 128 + dsw) = va;
      short8 vb = *(const short8*)(B + (size_t)(bcol + row) * K + kt * 64 + (cb >> 1));
      *(short8*)((char*)lB + row * 128 + dsw) = vb;
    }
    __syncthreads();
#pragma unroll
    for (int kk = 0; kk < 2; ++kk) {
      short8 af[4], bfr[2];
#pragma unroll
      for (int mt = 0; mt < 4; ++mt) {
        int row = wr * 64 + mt * 16 + r16;
        int byt = (kk * 64 + q * 16) ^ ((row & 7) << 4);
        af[mt] = *(const short8*)((const char*)lA + row * 128 + byt);
      }
#pragma unroll
      for (int nt = 0; nt < 2; ++nt) {
        int row = wc * 32 + nt * 16 + r16;
        int byt = (kk * 64 + q * 16) ^ ((row & 7) << 4);
        bfr[nt] = *(const short8*)((const char*)lB + row * 128 + byt);
      }
#pragma unroll
      for (int mt = 0; mt < 4; ++mt)
#pragma unroll
        for (int nt = 0; nt < 2; ++nt)
          acc[mt][nt] = mfma16(af[mt], bfr[nt], acc[mt][nt]);
    }
    __syncthreads();
  }

#pragma unroll
  for (int mt = 0; mt < 4; ++mt) {
#pragma unroll
    for (int nt = 0; nt < 2; ++nt) {
      int jc = bcol + wc * 32 + nt * 16 + r16;
      float bv = bias[jc];
      if (MODE == 0) {
#pragma unroll
        for (int rg = 0; rg < 4; ++rg) {
          int mg = brow + wr * 64 + mt * 16 + q * 4 + rg;
          ((float*)out)[(size_t)mg * N + jc] = acc[mt][nt][rg] + bv;
        }
      } else {
        int hB2 = jc >> 8;
        int jr  = jc & 255;
        int tidc = ((jr >> 5) << 6) + (((jr >> 2) & 3) << 4);  // + (bb&15)
        int colpart = ((jr >> 4) & 1) * 4 + (jc & 3);
#pragma unroll
        for (int rg = 0; rg < 4; ++rg) {
          int mg = brow + wr * 64 + mt * 16 + q * 4 + rg;
          int bb = mg >> 9;        // batch index (T=512)
          int t2 = mg & 511;       // time index
          int bx2 = hB2 * 8 + (bb >> 4);
          size_t idx = (((size_t)t2 * 16 + bx2) * 512 + tidc + (bb & 15)) * 8 + colpart;
          ((u16*)out)[idx] = f32_to_bf16(acc[mt][nt][rg] + bv);
        }
      }
    }
  }
}

// ---------------- Recurrence: h_t = tanh(U_t + h_{t-1} @ Whh^T) ----------------
// Pair j-split: 16 blocks = 8 batch groups x 2 column halves. Block bx = hB*8+g
// owns j in [hB*256, hB*256+256) for batch rows [g*16, g*16+16). 8 waves,
// 2/SIMD; per wave 32 j-cols -> W fully in registers (128 dwords, no spill,
// no W-LDS traffic). Own-half h via 16 KB LDS dbuf; partner half exchanged
// through a small global fragment ring with device-scope release/acquire.
__attribute__((amdgpu_flat_work_group_size(512, 512), amdgpu_waves_per_eu(2, 2)))
__global__ void rnn_rec2(const u16* __restrict__ Whh,
                         const u16* __restrict__ Ufrag,  // [512 t][16 bx][512 tid][8]
                         u16* __restrict__ Hout,         // [128][512][512] (rows 125..127 dump)
                         float* __restrict__ hidden,     // [125][512]
                         u16* __restrict__ Hx,           // [16 bx][16 ring][8 kk][4 q][16 m][8]
                         uint32_t* __restrict__ flags) { // [16]
  __shared__ u16 hlds[2 * 8 * 4 * 16 * 8];   // 16 KiB: [buf][kk][q][m][8]
  const int tid  = threadIdx.x;
  const int lane = tid & 63;
  const int w    = tid >> 6;          // 0..7
  const int q    = lane >> 4;
  const int r16  = lane & 15;
  const int bx   = blockIdx.x;
  const int hB   = bx >> 3;           // column half
  const int g    = bx & 7;            // batch group
  const int pbx  = bx ^ 8;            // partner block

  // ---- W registers: 2 j-tiles; own k-chunks at [0..8), partner at [8..16) ----
  const int kOwn = hB * 8, kPar = 8 - hB * 8;
  short8 wreg[2][16];
#pragma unroll
  for (int tt = 0; tt < 2; ++tt) {
    const u16* wrow = Whh + (size_t)(hB * 256 + w * 32 + tt * 16 + r16) * 512 + q * 8;
#pragma unroll
    for (int kkl = 0; kkl < 8; ++kkl) {
      wreg[tt][kkl]     = *(const short8*)(wrow + (kOwn + kkl) * 32);
      wreg[tt][8 + kkl] = *(const short8*)(wrow + (kPar + kkl) * 32);
    }
  }

  // ---- zero own-half h buf0 (8 KiB) ----
  {
    short8 z = {0, 0, 0, 0, 0, 0, 0, 0};
    *(short8*)((char*)hlds + tid * 16) = z;
  }
  __syncthreads();

  // ---- partner fragments start at zero (h_{-1} = 0) ----
  short8 pf[8];
#pragma unroll
  for (int i = 0; i < 8; ++i) pf[i] = (short8){0, 0, 0, 0, 0, 0, 0, 0};

  // ---- loop-invariant bases ----
  const char* ubase = (const char*)Ufrag + ((size_t)bx * 512 + tid) * 16;
  const int   jb    = hB * 256 + w * 32 + q * 4;
  const int   b     = g * 16 + r16;
  const bool  bok   = b < 125;
  u16*   hop  = Hout + (size_t)b * 262144 + jb;                    // += 512 per step
  float* hidp = hidden + (size_t)b * 512 + jb;
  // producer slot in fragment layout (u16 units): [kk=w][q'=tt*2+(q>>1)][m=r16][(q&1)*4]
  u16*       hxp = Hx + (size_t)bx * 65536 + w * 512 + (q >> 1) * 128 + r16 * 8 + (q & 1) * 4;
  const u16* hxc = Hx + (size_t)pbx * 65536 + q * 128 + r16 * 8;   // + kkl*512 + ring*4096
  uint32_t lrd = (q * 128 + r16 * 8) * 2;                          // byte, buf0
  uint32_t lwr = 8192 + (w * 512 + (q >> 1) * 128 + r16 * 8 + (q & 1) * 4) * 2;  // byte, buf1

  short8 u = *(const short8*)(ubase);

  for (int t = 0; t < 512; ++t) {
    // D init from U fragment
    f32x4 D0, D1;
#pragma unroll
    for (int rg = 0; rg < 4; ++rg) {
      D0[rg] = bf16_to_f32((u16)u[rg]);
      D1[rg] = bf16_to_f32((u16)u[rg + 4]);
    }
    // prefetch next step's U
    short8 nu = *(const short8*)(ubase + (size_t)((t < 511) ? (t + 1) : 511) * 131072);

    // own half (LDS), k-chunks kOwn..kOwn+7 -> wreg[..][0..8)
#pragma unroll
    for (int kkl = 0; kkl < 8; ++kkl) {
      short8 hf = *(const short8*)((const char*)hlds + lrd + kkl * 1024);
      D0 = mfma16(wreg[0][kkl], hf, D0);
      D1 = mfma16(wreg[1][kkl], hf, D1);
    }
    // partner half (regs, loaded end of previous step) -> wreg[..][8..16)
#pragma unroll
    for (int kkl = 0; kkl < 8; ++kkl) {
      D0 = mfma16(wreg[0][8 + kkl], pf[kkl], D0);
      D1 = mfma16(wreg[1][8 + kkl], pf[kkl], D1);
    }

    // epilogue: tanh -> pack -> LDS(next) + Hx(partner) + Hout
    u16* hxw = hxp + (t & 15) * 4096;
#pragma unroll
    for (int tt = 0; tt < 2; ++tt) {
      f32x4 Dt = tt ? D1 : D0;
      float e0 = tanh_e2(Dt[0]), e1 = tanh_e2(Dt[1]);
      float e2 = tanh_e2(Dt[2]), e3 = tanh_e2(Dt[3]);
      uint32_t lo = (uint32_t)f32_to_bf16(e0) | ((uint32_t)f32_to_bf16(e1) << 16);
      uint32_t hi = (uint32_t)f32_to_bf16(e2) | ((uint32_t)f32_to_bf16(e3) << 16);
      u32x2 pk; pk[0] = lo; pk[1] = hi;
      *(u32x2*)((char*)hlds + lwr + tt * 512) = pk;
      *(u32x2*)(hxw + tt * 256) = pk;
      *(u32x2*)(hop + tt * 16)  = pk;
      if (t == 511 && bok) {
        float4 v; v.x = e0; v.y = e1; v.z = e2; v.w = e3;
        *(float4*)(hidp + tt * 16) = v;
      }
    }
    hop += 512;

    // publish: all stores drained by syncthreads' waitcnt, then release flag
    __syncthreads();
    if (tid == 0)
      __hip_atomic_store(flags + bx, (uint32_t)(t + 1), __ATOMIC_RELEASE,
                         __HIP_MEMORY_SCOPE_AGENT);

    // wait partner's h_t, then load its fragments for next step
    {
      const uint32_t need = (uint32_t)(t + 1);
      while (__hip_atomic_load(flags + pbx, __ATOMIC_RELAXED,
                               __HIP_MEMORY_SCOPE_AGENT) < need)
        __builtin_amdgcn_s_sleep(1);
      __builtin_amdgcn_fence(__ATOMIC_ACQUIRE, "agent");
    }
    const u16* hxr = hxc + (t & 15) * 4096;
#pragma unroll
    for (int kkl = 0; kkl < 8; ++kkl)
      pf[kkl] = *(const short8*)(hxr + kkl * 512);

    u = nu;
    lrd ^= 8192; lwr ^= 8192;
  }
}

extern "C" void kernel_launch(void* const* d_in, const int* in_sizes, int n_in,
                              void* d_out, int out_size, void* d_ws, size_t ws_size,
                              hipStream_t stream) {
  const float* x   = (const float*)d_in[0];
  const float* wih = (const float*)d_in[1];   // [2,512,512]
  const float* whh = (const float*)d_in[2];   // [2,512,512]
  const float* bih = (const float*)d_in[3];   // [2,512]
  const float* bhh = (const float*)d_in[4];   // [2,512]
  const float* fcw = (const float*)d_in[5];   // [1024,512]
  const float* fcb = (const float*)d_in[6];   // [1024]

  // workspace layout
  char* ws = (char*)d_ws;
  u16* Xb    = (u16*)ws;                          // 65,536,000 B (dead after gemm1)
  u16* Hx    = (u16*)ws;                          // 2 MB exchange ring (reuses Xb region)
  uint32_t* flags = (uint32_t*)(ws + 2097152);    // 128 B (also inside dead Xb region)
  u16* Hb    = (u16*)(ws + 65536000);             // 67,108,864 B ([128][512][512])
  u16* Wih1  = (u16*)(ws + 132644864);            // 524,288 B each
  u16* Whh1  = Wih1 + 262144;
  u16* Wih2  = Whh1 + 262144;
  u16* Whh2  = Wih2 + 262144;
  u16* FCW   = Whh2 + 262144;                     // 1 MB
  float* b1  = (float*)(FCW + 524288);
  float* b2  = b1 + 512;

  // U scratch (fragment layout, 64 MB) lives in d_out; dead before FC writes
  u16*   Ubf  = (u16*)d_out;
  float* outp = (float*)d_out;
  float* hid  = outp + 65536000;                  // [2][125][512]

  conv_bf16<<<2048, 256, 0, stream>>>(x, Xb, 32768000L);
  conv_bf16<<<256, 256, 0, stream>>>(wih,          Wih1, 262144L);
  conv_bf16<<<256, 256, 0, stream>>>(wih + 262144, Wih2, 262144L);
  conv_bf16<<<256, 256, 0, stream>>>(whh,          Whh1, 262144L);
  conv_bf16<<<256, 256, 0, stream>>>(whh + 262144, Whh2, 262144L);
  conv_bf16<<<512, 256, 0, stream>>>(fcw, FCW, 524288L);
  prep_bias<<<1, 512, 0, stream>>>(bih, bhh, b1, b2);

  dim3 blk(512);
  dim3 g1(500, 4);   // 64000/128 x 512/128
  dim3 g2(500, 8);   // 64000/128 x 1024/128

  // layer 1
  gemm_bt<1><<<g1, blk, 0, stream>>>(Xb, Wih1, b1, Ubf, 64000, 512, 512);
  hipMemsetAsync(flags, 0, 128, stream);          // Xb dead now; init both flag arrays
  rnn_rec2<<<16, blk, 0, stream>>>(Whh1, Ubf, Hb, hid, Hx, flags);
  // layer 2
  gemm_bt<1><<<g1, blk, 0, stream>>>(Hb, Wih2, b2, Ubf, 64000, 512, 512);
  rnn_rec2<<<16, blk, 0, stream>>>(Whh2, Ubf, Hb, hid + 64000, Hx, flags + 16);
  // FC head
  gemm_bt<0><<<g2, blk, 0, stream>>>(Hb, FCW, fcb, d_out, 64000, 1024, 512);

  (void)in_sizes; (void)n_in; (void)out_size; (void)ws_size;
}

// Round 6
// 2596.756 us; speedup vs baseline: 1.3859x; 1.3859x over previous
//
#include <hip/hip_runtime.h>
#include <hip/hip_bf16.h>
#include <cstdint>

typedef short short8 __attribute__((ext_vector_type(8)));
typedef float f32x4 __attribute__((ext_vector_type(4)));
typedef uint32_t u32x2 __attribute__((ext_vector_type(2)));
typedef unsigned short u16;

#define DEVINL __device__ __forceinline__

DEVINL u16 f32_to_bf16(float f) {
  uint32_t u = __builtin_bit_cast(uint32_t, f);
  u += 0x7FFFu + ((u >> 16) & 1u);   // RTNE; inputs are finite
  return (u16)(u >> 16);
}
DEVINL float bf16_to_f32(u16 b) {
  return __builtin_bit_cast(float, ((uint32_t)b) << 16);
}
DEVINL f32x4 mfma16(short8 a, short8 b, f32x4 c) {
  return __builtin_amdgcn_mfma_f32_16x16x32_bf16(a, b, c, 0, 0, 0);
}
// tanh(x) = 1 - 2/(1+e^{2x}); e^{2x} = exp2(x * 2*log2(e)). Inf-safe at both ends.
DEVINL float tanh_e2(float x) {
  float e = __builtin_amdgcn_exp2f(x * 2.88539008177793f);
  return 1.f - __fdividef(2.f, 1.f + e);
}
// packed f32x2 -> bf16x2 (RTNE), 1 instr instead of ~6
DEVINL uint32_t cvt_pk_bf16(float lo, float hi) {
  uint32_t r;
  asm("v_cvt_pk_bf16_f32 %0, %1, %2" : "=v"(r) : "v"(lo), "v"(hi));
  return r;
}

// ---------------- fp32 -> bf16 convert ----------------
__global__ void conv_bf16(const float* __restrict__ src, u16* __restrict__ dst, long n) {
  long i = ((long)blockIdx.x * blockDim.x + threadIdx.x) * 4;
  long stride = (long)gridDim.x * blockDim.x * 4;
  for (; i < n; i += stride) {
    float4 v = *(const float4*)(src + i);
    uint64_t p = (uint64_t)f32_to_bf16(v.x)
               | ((uint64_t)f32_to_bf16(v.y) << 16)
               | ((uint64_t)f32_to_bf16(v.z) << 32)
               | ((uint64_t)f32_to_bf16(v.w) << 48);
    *(uint64_t*)(dst + i) = p;
  }
}

__global__ void prep_bias(const float* __restrict__ bih, const float* __restrict__ bhh,
                          float* __restrict__ b1, float* __restrict__ b2) {
  int i = threadIdx.x;   // 512 threads
  b1[i] = bih[i]       + bhh[i];
  b2[i] = bih[512 + i] + bhh[512 + i];
}

// ---------------- GEMM: C[M,N] = A[M,K] @ B[N,K]^T + bias ----------------
// MODE 0: float out, [M][N] (FC head).
// MODE 1: bf16 out scattered into rec's U fragment layout (512-thread consumer):
//   (b,t,j): tid = (j>>6)*64 + ((j>>2)&3)*16 + (b&15)
//   idx = ((t*8 + (b>>4))*512 + tid)*16 + ((j>>4)&3)*4 + (j&3)
template <int MODE>
__launch_bounds__(512, 2)
__global__ void gemm_bt(const u16* __restrict__ A, const u16* __restrict__ B,
                        const float* __restrict__ bias, void* __restrict__ out,
                        int M, int N, int K) {
  __shared__ u16 lA[128 * 64];
  __shared__ u16 lB[128 * 64];
  const int tid  = threadIdx.x;
  const int lane = tid & 63;
  const int wave = tid >> 6;
  const int wr = wave >> 2;
  const int wc = wave & 3;
  const int q   = lane >> 4;
  const int r16 = lane & 15;
  const int brow = blockIdx.x * 128;
  const int bcol = blockIdx.y * 128;

  f32x4 acc[4][2];
#pragma unroll
  for (int i = 0; i < 4; ++i)
#pragma unroll
    for (int j = 0; j < 2; ++j) acc[i][j] = (f32x4){0.f, 0.f, 0.f, 0.f};

  const int nkt = K >> 6;
  for (int kt = 0; kt < nkt; ++kt) {
#pragma unroll
    for (int s = 0; s < 2; ++s) {
      int c   = tid * 2 + s;
      int row = c >> 3;
      int cb  = (c & 7) * 16;
      int dsw = cb ^ ((row & 7) << 4);
      short8 va = *(const short8*)(A + (size_t)(brow + row) * K + kt * 64 + (cb >> 1));
      *(short8*)((char*)lA + row * 128 + dsw) = va;
      short8 vb = *(const short8*)(B + (size_t)(bcol + row) * K + kt * 64 + (cb >> 1));
      *(short8*)((char*)lB + row * 128 + dsw) = vb;
    }
    __syncthreads();
#pragma unroll
    for (int kk = 0; kk < 2; ++kk) {
      short8 af[4], bfr[2];
#pragma unroll
      for (int mt = 0; mt < 4; ++mt) {
        int row = wr * 64 + mt * 16 + r16;
        int byt = (kk * 64 + q * 16) ^ ((row & 7) << 4);
        af[mt] = *(const short8*)((const char*)lA + row * 128 + byt);
      }
#pragma unroll
      for (int nt = 0; nt < 2; ++nt) {
        int row = wc * 32 + nt * 16 + r16;
        int byt = (kk * 64 + q * 16) ^ ((row & 7) << 4);
        bfr[nt] = *(const short8*)((const char*)lB + row * 128 + byt);
      }
#pragma unroll
      for (int mt = 0; mt < 4; ++mt)
#pragma unroll
        for (int nt = 0; nt < 2; ++nt)
          acc[mt][nt] = mfma16(af[mt], bfr[nt], acc[mt][nt]);
    }
    __syncthreads();
  }

#pragma unroll
  for (int mt = 0; mt < 4; ++mt) {
#pragma unroll
    for (int nt = 0; nt < 2; ++nt) {
      int jc = bcol + wc * 32 + nt * 16 + r16;
      float bv = bias[jc];
      if (MODE == 0) {
#pragma unroll
        for (int rg = 0; rg < 4; ++rg) {
          int mg = brow + wr * 64 + mt * 16 + q * 4 + rg;
          ((float*)out)[(size_t)mg * N + jc] = acc[mt][nt][rg] + bv;
        }
      } else {
        int tidc    = (jc >> 6) * 64 + ((jc >> 2) & 3) * 16;   // + (bb&15)
        int colpart = ((jc >> 4) & 3) * 4 + (jc & 3);
#pragma unroll
        for (int rg = 0; rg < 4; ++rg) {
          int mg = brow + wr * 64 + mt * 16 + q * 4 + rg;
          int bb = mg >> 9;        // batch index (T=512)
          int t2 = mg & 511;       // time index
          size_t idx = (((size_t)t2 * 8 + (bb >> 4)) * 512 + tidc + (bb & 15)) * 16 + colpart;
          ((u16*)out)[idx] = f32_to_bf16(acc[mt][nt][rg] + bv);
        }
      }
    }
  }
}

// ---------------- Recurrence: h_t = tanh(U_t + h_{t-1} @ Whh^T) ----------------
// 8 blocks (16 batch rows each), 8 waves, EXACTLY 2 waves/SIMD (256-reg budget).
// Wave w owns j-cols [w*64, w*64+64): tiles 0..2 PINNED TO AGPRs (192 regs),
// tile 3 in LDS. LDS: W 128 KiB ([kk][q][r16][16B] per wave) + h dbuf 32 KiB.
// AGPR pin leaves ~64 arch VGPRs for the ds_read pipeline (round-4 starved it).
// Single U buffer (u dead after D-init -> reused for prefetch). 32-bit offsets.
// Raw barrier (lgkmcnt only): global U-loads / H-stores never drained in-loop.
__attribute__((amdgpu_flat_work_group_size(512, 512), amdgpu_waves_per_eu(2, 2)))
__global__ void rnn_rec(const u16* __restrict__ Whh,
                        const u16* __restrict__ Ufrag,
                        u16* __restrict__ Hout,     // [128][512][512] bf16 (rows 125..127 dump)
                        float* __restrict__ hidden) {
  __shared__ char LDS[163840];
  // [0,131072): W LDS tiles, wave w at w*16384, addr = kk*1024 + q*256 + r16*16
  // [131072,147456): h buf0   [147456,163840): h buf1, layout [kk][q][m(r16)][16B]
  const int tid  = threadIdx.x;
  const int lane = tid & 63;
  const int w    = tid >> 6;          // 0..7
  const int q    = lane >> 4;
  const int r16  = lane & 15;
  const int g    = blockIdx.x;

  // ---- W register tiles 0..2 (j = w*64 + tt*16 + r16), pinned to AGPRs ----
  short8 wreg[3][16];
#pragma unroll
  for (int tt = 0; tt < 3; ++tt)
#pragma unroll
    for (int kk = 0; kk < 16; ++kk) {
      wreg[tt][kk] = *(const short8*)(Whh + (size_t)(w * 64 + tt * 16 + r16) * 512 + kk * 32 + q * 8);
      asm volatile("" : "+a"(wreg[tt][kk]));   // force AGPR residency
    }

  // ---- W LDS tile 3 (j = w*64 + 48 + r16) ----
#pragma unroll
  for (int kk = 0; kk < 16; ++kk) {
    short8 v = *(const short8*)(Whh + (size_t)(w * 64 + 48 + r16) * 512 + kk * 32 + q * 8);
    *(short8*)(LDS + w * 16384 + kk * 1024 + q * 256 + r16 * 16) = v;
  }

  // ---- zero h buf0 ----
  {
    short8 z = {0, 0, 0, 0, 0, 0, 0, 0};
    *(short8*)(LDS + 131072 + tid * 32)      = z;
    *(short8*)(LDS + 131072 + tid * 32 + 16) = z;
  }

  // ---- loop-invariant bases (32-bit offsets; uniform kernel-arg bases) ----
  uint32_t rd = 131072 + q * 256 + r16 * 16;                 // h read base (buf0)
  uint32_t wr = 147456 + w * 2048 + (q >> 1) * 256 + r16 * 16 + (q & 1) * 8;  // write (buf1)
  const uint32_t wlb = w * 16384 + q * 256 + r16 * 16;       // W LDS base
  const int jb = w * 64 + q * 4;
  const char* Ub = (const char*)Ufrag;
  const uint32_t ubase = (uint32_t)(g * 512 + tid) * 32;
  char* Hc = (char*)Hout;
  uint32_t hoff = (uint32_t)(g * 16 + r16) * 524288u + (uint32_t)jb * 2u;  // += 1024/step

  // ---- prologue: u=U[0]; D-init(0); issue u=U[1]; barrier ----
  short8 u = *(const short8*)(Ub + ubase);
  f32x4 D0, D1, D2, D3;
#pragma unroll
  for (int rg = 0; rg < 4; ++rg) {
    D0[rg] = bf16_to_f32((u16)u[rg]);
    D1[rg] = bf16_to_f32((u16)u[rg + 4]);
  }
  {
    uint32_t uhi0 = __builtin_bit_cast(uint32_t, (float)0);  // silence unused path
    (void)uhi0;
  }
#pragma unroll
  for (int rg = 0; rg < 4; ++rg) {
    // u1 half lives in the upper 4 slots of the same short8 pair layout:
  }
  // full D-init (tiles 0,1 from low 8 u16; tiles 2,3 from high 8): reload view
  {
    const short8 uv = u;
#pragma unroll
    for (int rg = 0; rg < 4; ++rg) {
      D2[rg] = bf16_to_f32((u16)uv[rg]);     // placeholder, overwritten below
      D3[rg] = bf16_to_f32((u16)uv[rg]);
    }
  }
  // NOTE: U layout: 16 u16 per thread per step = two short8 loads. Use b128 pair.
  short8 u2 = *(const short8*)(Ub + ubase + 16);
#pragma unroll
  for (int rg = 0; rg < 4; ++rg) {
    D2[rg] = bf16_to_f32((u16)u2[rg]);
    D3[rg] = bf16_to_f32((u16)u2[rg + 4]);
  }
  // issue U[1] prefetch into (u,u2)
  u  = *(const short8*)(Ub + ubase + 131072u);
  u2 = *(const short8*)(Ub + ubase + 131072u + 16);
  __syncthreads();

  for (int t = 0; t < 512; ++t) {
    // merged kk loop: 1 hf + 1 wl read, 4 MFMAs (wreg from AGPR)
#pragma unroll
    for (int kk = 0; kk < 16; ++kk) {
      short8 hf = *(const short8*)(LDS + rd + kk * 1024);
      short8 wl = *(const short8*)(LDS + wlb + kk * 1024);
      D0 = mfma16(wreg[0][kk], hf, D0);
      D1 = mfma16(wreg[1][kk], hf, D1);
      D2 = mfma16(wreg[2][kk], hf, D2);
      D3 = mfma16(wl, hf, D3);
    }

    // epilogue: tanh -> cvt_pk pack -> LDS h(next) + global H
#define EPI_TILE(Dt, tt) { \
    float e0 = tanh_e2(Dt[0]), e1 = tanh_e2(Dt[1]); \
    float e2 = tanh_e2(Dt[2]), e3 = tanh_e2(Dt[3]); \
    u32x2 pk; pk[0] = cvt_pk_bf16(e0, e1); pk[1] = cvt_pk_bf16(e2, e3); \
    *(u32x2*)(LDS + wr + ((tt) >> 1) * 1024 + ((tt) & 1) * 512) = pk; \
    *(u32x2*)(Hc + hoff + (tt) * 32) = pk; \
  }
    EPI_TILE(D0, 0); EPI_TILE(D1, 1); EPI_TILE(D2, 2); EPI_TILE(D3, 3);
#undef EPI_TILE
    hoff += 1024;

    // D-init(t+1) from prefetched u (pre-barrier: VALU hides under convergence),
    // then reuse u as the t+2 prefetch buffer.
    if (t < 511) {
#pragma unroll
      for (int rg = 0; rg < 4; ++rg) {
        D0[rg] = bf16_to_f32((u16)u[rg]);
        D1[rg] = bf16_to_f32((u16)u[rg + 4]);
        D2[rg] = bf16_to_f32((u16)u2[rg]);
        D3[rg] = bf16_to_f32((u16)u2[rg + 4]);
      }
      uint32_t off = ubase + (uint32_t)((t + 2 <= 511) ? (t + 2) : 511) * 131072u;
      u  = *(const short8*)(Ub + off);
      u2 = *(const short8*)(Ub + off + 16);
    }

    rd ^= 16384; wr ^= 16384;   // swap h buffers
    asm volatile("s_waitcnt lgkmcnt(0)" ::: "memory");
    __builtin_amdgcn_s_barrier();
    asm volatile("" ::: "memory");
  }

  // ---- final hidden state: h(T-1) is in buf0 (512 swaps); read own slots ----
  {
    int b = g * 16 + r16;
    if (b < 125) {
      uint32_t fwr = 131072 + w * 2048 + (q >> 1) * 256 + r16 * 16 + (q & 1) * 8;
#pragma unroll
      for (int tt = 0; tt < 4; ++tt) {
        u32x2 pk = *(const u32x2*)(LDS + fwr + (tt >> 1) * 1024 + (tt & 1) * 512);
        float4 v;
        v.x = __builtin_bit_cast(float, pk[0] << 16);
        v.y = __builtin_bit_cast(float, pk[0] & 0xFFFF0000u);
        v.z = __builtin_bit_cast(float, pk[1] << 16);
        v.w = __builtin_bit_cast(float, pk[1] & 0xFFFF0000u);
        *(float4*)(hidden + (size_t)b * 512 + jb + tt * 16) = v;
      }
    }
  }
}

extern "C" void kernel_launch(void* const* d_in, const int* in_sizes, int n_in,
                              void* d_out, int out_size, void* d_ws, size_t ws_size,
                              hipStream_t stream) {
  const float* x   = (const float*)d_in[0];
  const float* wih = (const float*)d_in[1];   // [2,512,512]
  const float* whh = (const float*)d_in[2];   // [2,512,512]
  const float* bih = (const float*)d_in[3];   // [2,512]
  const float* bhh = (const float*)d_in[4];   // [2,512]
  const float* fcw = (const float*)d_in[5];   // [1024,512]
  const float* fcb = (const float*)d_in[6];   // [1024]

  // workspace layout
  char* ws = (char*)d_ws;
  u16* Xb    = (u16*)ws;                          // 65,536,000 B
  u16* Hb    = (u16*)(ws + 65536000);             // 67,108,864 B ([128][512][512])
  u16* Wih1  = (u16*)(ws + 132644864);            // 524,288 B each
  u16* Whh1  = Wih1 + 262144;
  u16* Wih2  = Whh1 + 262144;
  u16* Whh2  = Wih2 + 262144;
  u16* FCW   = Whh2 + 262144;                     // 1 MB
  float* b1  = (float*)(FCW + 524288);
  float* b2  = b1 + 512;

  // U scratch (fragment layout, 64 MB) lives in d_out; dead before FC writes
  u16*   Ubf  = (u16*)d_out;
  float* outp = (float*)d_out;
  float* hid  = outp + 65536000;                  // [2][125][512]

  conv_bf16<<<2048, 256, 0, stream>>>(x, Xb, 32768000L);
  conv_bf16<<<256, 256, 0, stream>>>(wih,          Wih1, 262144L);
  conv_bf16<<<256, 256, 0, stream>>>(wih + 262144, Wih2, 262144L);
  conv_bf16<<<256, 256, 0, stream>>>(whh,          Whh1, 262144L);
  conv_bf16<<<256, 256, 0, stream>>>(whh + 262144, Whh2, 262144L);
  conv_bf16<<<512, 256, 0, stream>>>(fcw, FCW, 524288L);
  prep_bias<<<1, 512, 0, stream>>>(bih, bhh, b1, b2);

  dim3 blk(512);
  dim3 g1(500, 4);   // 64000/128 x 512/128
  dim3 g2(500, 8);   // 64000/128 x 1024/128

  // layer 1
  gemm_bt<1><<<g1, blk, 0, stream>>>(Xb, Wih1, b1, Ubf, 64000, 512, 512);
  rnn_rec<<<8, 512, 0, stream>>>(Whh1, Ubf, Hb, hid);
  // layer 2
  gemm_bt<1><<<g1, blk, 0, stream>>>(Hb, Wih2, b2, Ubf, 64000, 512, 512);
  rnn_rec<<<8, 512, 0, stream>>>(Whh2, Ubf, Hb, hid + 64000);
  // FC head
  gemm_bt<0><<<g2, blk, 0, stream>>>(Hb, FCW, fcb, d_out, 64000, 1024, 512);

  (void)in_sizes; (void)n_in; (void)out_size; (void)ws_size;
}